// Round 3
// baseline (23.846 us; speedup 1.0000x reference)
//
#include <hip/hip_runtime.h>
#include <math.h>

#define NB    512
#define DXN   100
#define MROW  128
#define TC    130
#define G     16
#define BT    512
#define KP    128            // padded K for the MFMA GEMM
#define APAD  136            // LDS A row stride (elements) -> 272 B, breaks bank conflicts
#define T0f   (-5.0f)
#define Hf    (10.0f / 99.0f)
#define LOG2E 1.4426950408889634f
#define WLO   42
#define WHI   67
#define WN    (WHI - WLO + 1)   // 26

typedef __attribute__((ext_vector_type(8))) short  short8;   // 8 bf16 = 4 VGPR
typedef __attribute__((ext_vector_type(4))) float  f32x4;

__device__ __forceinline__ float Tval(int t) { return T0f + Hf * (float)t; }

__device__ __forceinline__ unsigned short bf16_rne(float x) {
    unsigned u = __float_as_uint(x);
    return (unsigned short)((u + 0x7FFF + ((u >> 16) & 1)) >> 16);
}
__device__ __forceinline__ float bf16_to_f(unsigned short h) {
    return __uint_as_float(((unsigned)h) << 16);
}

// ---- Kernel 1: B matrix = phi1^T scaled, as bf16 hi/lo, [n][k] layout (k contiguous) ----
// B[n][k] = INV_SQRT_2PI / sigma[n] * exp(-0.5 * ((mu[n]-T[k])/sigma[n])^2), k<100; 0 pad to 128.
__global__ __launch_bounds__(64) void phi_kernel(
    const float* __restrict__ mu, const float* __restrict__ sigma,
    unsigned* __restrict__ Bh32, unsigned* __restrict__ Bl32)
{
    const int n = blockIdx.x;       // 512 blocks, one column each
    const int j = threadIdx.x;      // 64 threads, 2 k's each
    float mun   = mu[n];
    float inv_s = 1.0f / sigma[n];
    float scale = 0.3989422804014327f * inv_s;
    const float Lh = 0.5f * LOG2E;
    unsigned h = 0, l = 0;
    #pragma unroll
    for (int s = 0; s < 2; ++s) {
        int t = 2 * j + s;
        float p = 0.0f;
        if (t < DXN) {
            float u = (mun - Tval(t)) * inv_s;
            p = scale * __builtin_amdgcn_exp2f(-Lh * u * u);
        }
        unsigned short ph = bf16_rne(p);
        unsigned short pl = bf16_rne(p - bf16_to_f(ph));
        h |= ((unsigned)ph) << (16 * s);
        l |= ((unsigned)pl) << (16 * s);
    }
    Bh32[n * 64 + j] = h;
    Bl32[n * 64 + j] = l;
}

// ---- Kernel 2: theta -> dw (fp32 + bf16 hi/lo in LDS) -> MFMA GEMM vs B -> out ----
__global__ __launch_bounds__(BT) void main_kernel(
    const float* __restrict__ theta,
    const unsigned short* __restrict__ Bh,
    const unsigned short* __restrict__ Bl,
    float* __restrict__ out, int Bn)
{
    __shared__ float s_alpha[G][MROW];           // 8 KB
    __shared__ float s_th0[G], s_th1[G], s_muc[G], s_negth1[G];
    __shared__ float s_f[G][WN];
    __shared__ float s_dwf[DXN][G];              // fp32 dw, for exact Z
    __shared__ unsigned short sAh[G * APAD];     // A hi (bf16 bits), padded rows
    __shared__ unsigned short sAl[G * APAD];     // A lo
    __shared__ float s_invZ[G];

    const int tid  = threadIdx.x;
    const int b0   = blockIdx.x * G;
    const int lane = tid & 63;
    const int wv   = tid >> 6;                   // wave 0..7 -> 64-col slab
    const int lrow = lane & 15;
    const int kg   = (lane >> 4) * 8;            // k-group within 32

    // ---- Phase A: stage G theta rows ----
    for (int i = tid; i < G * TC; i += BT) {
        int r = i / TC, c = i - r * TC;
        int br = b0 + r; if (br >= Bn) br = Bn - 1;
        float v = theta[br * TC + c];
        if (c >= 2)      s_alpha[r][c - 2] = v;
        else if (c == 0) s_th0[r] = v;
        else             s_th1[r] = v;
    }
    __syncthreads();

    // ---- Phase B0: per-row scalars ----
    if (tid < G) {
        float th1 = s_th1[tid];
        s_muc[tid]    = s_th0[tid] * (-0.5f / th1);
        s_negth1[tid] = -th1;
    }
    // ---- Phase B1: f(r,t) on the K-active window via exp2 recurrence ----
    if (tid < G * WN) {
        int r = tid / WN;
        int t = WLO + (tid - r * WN);
        float T = Tval(t);
        const float C2 = 50.0f * LOG2E;
        const float dj = 1.0f / 127.0f;
        float d0 = -T;
        float a  = -C2 * d0 * d0;
        float bb = -C2 * dj * (2.0f * d0 + dj);
        const float cc = -2.0f * C2 * dj * dj;
        const float* al = s_alpha[r];
        float f = 0.0f;
        for (int jc = 0; jc < MROW / 4; ++jc) {
            float4 av = *(const float4*)&al[4 * jc];
            f += av.x * __builtin_amdgcn_exp2f(a); a += bb; bb += cc;
            f += av.y * __builtin_amdgcn_exp2f(a); a += bb; bb += cc;
            f += av.z * __builtin_amdgcn_exp2f(a); a += bb; bb += cc;
            f += av.w * __builtin_amdgcn_exp2f(a); a += bb; bb += cc;
        }
        s_f[r][t - WLO] = f;
    }
    __syncthreads();

    // ---- Phase B2: dw -> fp32 LDS + bf16 hi/lo A tile (+ zero pad k=100..127) ----
    for (int task = tid; task < G * KP; task += BT) {     // 2048 tasks
        if (task < G * DXN) {
            int t = task >> 4;            // G == 16
            int r = task & (G - 1);
            float f = (t >= WLO && t <= WHI) ? s_f[r][t - WLO] : 0.0f;
            float dmu  = s_muc[r] - Tval(t);
            float quad = s_negth1[r] * dmu * dmu;
            float e = fmaxf(1.0f + f - quad, 1e-8f);
            float w = Hf; if (t == 0 || t == DXN - 1) w *= 0.5f;
            float dw = e * w;
            s_dwf[t][r] = dw;
            unsigned short h = bf16_rne(dw);
            sAh[r * APAD + t] = h;
            sAl[r * APAD + t] = bf16_rne(dw - bf16_to_f(h));
        } else {
            int idx = task - G * DXN;     // 448 pad tasks
            int r = idx / (KP - DXN);
            int k = DXN + idx % (KP - DXN);
            sAh[r * APAD + k] = 0;
            sAl[r * APAD + k] = 0;
        }
    }
    __syncthreads();

    // ---- Phase C (wave 0 fringe): Z per row in fp32 ----
    if (tid < G) {
        float z = 0.0f;
        for (int t = 0; t < DXN; ++t) z += s_dwf[t][tid];
        s_invZ[tid] = 1.0f / z;
    }

    // ---- Phase D: MFMA GEMM. Wave wv covers cols [wv*64, wv*64+64) as 4 16-col tiles ----
    short8 Ahf[4], Alf[4];
    #pragma unroll
    for (int ks = 0; ks < 4; ++ks) {
        Ahf[ks] = *(const short8*)&sAh[lrow * APAD + ks * 32 + kg];
        Alf[ks] = *(const short8*)&sAl[lrow * APAD + ks * 32 + kg];
    }

    f32x4 acc[4];
    #pragma unroll
    for (int t = 0; t < 4; ++t) {
        const int n = wv * 64 + t * 16 + lrow;          // this lane's B column
        const unsigned short* bp = Bh + n * KP + kg;
        const unsigned short* bq = Bl + n * KP + kg;
        short8 bh[4], bl[4];
        #pragma unroll
        for (int ks = 0; ks < 4; ++ks) {
            bh[ks] = *(const short8*)(bp + ks * 32);
            bl[ks] = *(const short8*)(bq + ks * 32);
        }
        f32x4 a = {0.0f, 0.0f, 0.0f, 0.0f};
        #pragma unroll
        for (int ks = 0; ks < 4; ++ks) {
            a = __builtin_amdgcn_mfma_f32_16x16x32_bf16(Ahf[ks], bh[ks], a, 0, 0, 0);
            a = __builtin_amdgcn_mfma_f32_16x16x32_bf16(Alf[ks], bh[ks], a, 0, 0, 0);
            a = __builtin_amdgcn_mfma_f32_16x16x32_bf16(Ahf[ks], bl[ks], a, 0, 0, 0);
        }
        acc[t] = a;
    }
    __syncthreads();   // s_invZ visible

    // ---- Epilogue: out[row][col] = acc * invZ[row]  (sigma scale folded into B) ----
    f32x4 invZ4 = *(const f32x4*)&s_invZ[(lane >> 4) * 4];
    #pragma unroll
    for (int t = 0; t < 4; ++t) {
        int col = wv * 64 + t * 16 + lrow;
        #pragma unroll
        for (int j = 0; j < 4; ++j) {
            int row = b0 + (lane >> 4) * 4 + j;
            if (row < Bn) out[row * NB + col] = acc[t][j] * invZ4[j];
        }
    }
}

extern "C" void kernel_launch(void* const* d_in, const int* in_sizes, int n_in,
                              void* d_out, int out_size, void* d_ws, size_t ws_size,
                              hipStream_t stream) {
    const float* theta = (const float*)d_in[0];
    const float* mu    = (const float*)d_in[1];
    const float* sigma = (const float*)d_in[2];
    float* outp = (float*)d_out;

    unsigned short* Bh = (unsigned short*)d_ws;            // 512*128*2 B = 128 KB
    unsigned short* Bl = Bh + NB * KP;                     // +128 KB
    int Bn = in_sizes[0] / TC;                             // 4096

    phi_kernel<<<NB, 64, 0, stream>>>(mu, sigma, (unsigned*)Bh, (unsigned*)Bl);
    main_kernel<<<(Bn + G - 1) / G, BT, 0, stream>>>(theta, Bh, Bl, outp, Bn);
}